// Round 15
// baseline (347.059 us; speedup 1.0000x reference)
//
#include <hip/hip_runtime.h>
#include <hip/hip_bf16.h>
#include <cstdint>

#define L_SEQ   2048
#define BATCH   2
#define ROWS    (BATCH*L_SEQ)     // 4096
#define DMODEL  1024
#define DINNER  2048
#define DSTATE  128
#define NHEADS  32
#define DIN_PROJ 4384
#define DIN_PAD  4480             // padded to multiple of 128 for BN tiles
#define CONVDIM  2304
#define DMLP    4096
#define CHUNK   64
#define NCHUNK  (L_SEQ/CHUNK)     // 32

typedef __attribute__((ext_vector_type(4))) float f32x4;
typedef __attribute__((ext_vector_type(8))) short bf16x8;
typedef __attribute__((ext_vector_type(4))) short bf16x4;
typedef __attribute__((ext_vector_type(2))) short bf16x2;

static __device__ __forceinline__ short f2bf(float f) {
  union { float f; unsigned int i; } v; v.f = f;
  unsigned int r = v.i + 0x7fffu + ((v.i >> 16) & 1u);  // round-to-nearest-even
  return (short)(r >> 16);
}
static __device__ __forceinline__ float bf2f(short s) {
  union { unsigned int i; float f; } v; v.i = ((unsigned int)(unsigned short)s) << 16;
  return v.f;
}

static __device__ __forceinline__ void gl2lds16(const void* g, void* l) {
  __builtin_amdgcn_global_load_lds((const __attribute__((address_space(1))) void*)g,
                                   (__attribute__((address_space(3))) void*)l, 16, 0, 0);
}

// ---------------- merged fp32 -> bf16 weight convert (4 weights, 1 launch) ----------------
__global__ __launch_bounds__(256) void cvt_all_kernel(
    const float* __restrict__ w1, const float* __restrict__ w2,
    const float* __restrict__ w3, const float* __restrict__ w4,
    short* __restrict__ d1, short* __restrict__ d2,
    short* __restrict__ d3, short* __restrict__ d4)
{
  int b = blockIdx.x;
  const float* src; short* dst; long rows_src; int kshift;
  if (b < 4480)       { src = w1; dst = d1; rows_src = DIN_PROJ; kshift = 10; }
  else if (b < 6528)  { src = w2; dst = d2; rows_src = DMODEL;   kshift = 11; b -= 4480; }
  else if (b < 10624) { src = w3; dst = d3; rows_src = DMLP;     kshift = 10; b -= 6528; }
  else                { src = w4; dst = d4; rows_src = DMODEL;   kshift = 12; b -= 10624; }
  long i = ((long)b * 256 + threadIdx.x) * 4;
  long r = i >> kshift;
  bf16x4 o;
  if (r < rows_src) {
    f32x4 v = *(const f32x4*)&src[i];
    o[0] = f2bf(v[0]); o[1] = f2bf(v[1]); o[2] = f2bf(v[2]); o[3] = f2bf(v[3]);
  } else {
    o[0] = 0; o[1] = 0; o[2] = 0; o[3] = 0;
  }
  *(bf16x4*)&dst[i] = o;
}

// ---------------- L2-style norm: w * x * rsqrt(sum(x^2) + 1e-6), D=1024 -> bf16 ----------------
__global__ __launch_bounds__(256) void rmsnorm_l2_kernel(const float* __restrict__ in,
                                                         const float* __restrict__ w,
                                                         short* __restrict__ out)
{
  int row = blockIdx.x, tid = threadIdx.x;
  const float* xr = in + (long)row * DMODEL;
  f32x4 v = *(const f32x4*)&xr[tid * 4];
  float s = v[0]*v[0] + v[1]*v[1] + v[2]*v[2] + v[3]*v[3];
  for (int o = 32; o; o >>= 1) s += __shfl_down(s, o);
  __shared__ float red[4];
  if ((tid & 63) == 0) red[tid >> 6] = s;
  __syncthreads();
  float sc = rsqrtf(red[0] + red[1] + red[2] + red[3] + 1e-6f);
  f32x4 wv = *(const f32x4*)&w[tid * 4];
  bf16x4 o;
  #pragma unroll
  for (int j = 0; j < 4; j++) o[j] = f2bf(v[j] * sc * wv[j]);
  *(bf16x4*)&out[(long)row * DMODEL + tid * 4] = o;
}

// ---- fused: X2 = sum4(PART bf16)+x ; X2NB = norm2(X2) ----
__global__ __launch_bounds__(256) void reduce_norm_kernel(
    const short* __restrict__ part, const float* __restrict__ resid,
    const float* __restrict__ w, float* __restrict__ X2, short* __restrict__ out)
{
  int row = blockIdx.x, tid = threadIdx.x;
  long i = (long)row * DMODEL + tid * 4;
  const long MN = (long)ROWS * DMODEL;
  bf16x4 p0 = *(const bf16x4*)&part[i];
  bf16x4 p1 = *(const bf16x4*)&part[i + MN];
  bf16x4 p2 = *(const bf16x4*)&part[i + 2*MN];
  bf16x4 p3 = *(const bf16x4*)&part[i + 3*MN];
  f32x4 r = *(const f32x4*)&resid[i];
  f32x4 v;
  float s = 0.f;
  #pragma unroll
  for (int j = 0; j < 4; j++) {
    v[j] = (bf2f(p0[j]) + bf2f(p1[j])) + (bf2f(p2[j]) + bf2f(p3[j])) + r[j];
    s += v[j] * v[j];
  }
  *(f32x4*)&X2[i] = v;
  for (int o = 32; o; o >>= 1) s += __shfl_down(s, o);
  __shared__ float red[4];
  if ((tid & 63) == 0) red[tid >> 6] = s;
  __syncthreads();
  float sc = rsqrtf(red[0] + red[1] + red[2] + red[3] + 1e-6f);
  f32x4 wv = *(const f32x4*)&w[tid * 4];
  bf16x4 o;
  #pragma unroll
  for (int j = 0; j < 4; j++) o[j] = f2bf(v[j] * sc * wv[j]);
  *(bf16x4*)&out[i] = o;
}

// ---------------- split-4 reduce (final): out = sum(p_s bf16) + resid + bias, f32 ----------------
__global__ __launch_bounds__(256) void reduce_split4_kernel(
    const short* __restrict__ part, const float* __restrict__ resid,
    const float* __restrict__ bias, float* __restrict__ out)
{
  long i = ((long)blockIdx.x * 256 + threadIdx.x) * 8;
  const long MN = (long)ROWS * DMODEL;
  bf16x8 p0 = *(const bf16x8*)&part[i];
  bf16x8 p1 = *(const bf16x8*)&part[i + MN];
  bf16x8 p2 = *(const bf16x8*)&part[i + 2*MN];
  bf16x8 p3 = *(const bf16x8*)&part[i + 3*MN];
  f32x4 r0 = *(const f32x4*)&resid[i];
  f32x4 r1 = *(const f32x4*)&resid[i + 4];
  int c = (int)(i & (DMODEL - 1));
  f32x4 b0 = *(const f32x4*)&bias[c];
  f32x4 b1 = *(const f32x4*)&bias[c + 4];
  f32x4 o0, o1;
  #pragma unroll
  for (int j = 0; j < 4; j++) {
    o0[j] = (bf2f(p0[j]) + bf2f(p1[j])) + (bf2f(p2[j]) + bf2f(p3[j])) + r0[j] + b0[j];
    o1[j] = (bf2f(p0[j+4]) + bf2f(p1[j+4])) + (bf2f(p2[j+4]) + bf2f(p3[j+4])) + r1[j] + b1[j];
  }
  *(f32x4*)&out[i] = o0;
  *(f32x4*)&out[i + 4] = o1;
}

// ------- bf16 GEMM, 128x128 tile, BK=64, single-buffer + T2 swizzle, PLAIN __syncthreads -------
// m97/m103 structure (874-912 TF measured): NO manual waitcnt/sched_barrier — the compiler
// auto-drains vmcnt before barriers and emits fine-grained lgkmcnt for ds_read->MFMA
// (m141: manual schedule-pinning = 510 TF regression; this is the A/B for that).
// Split-K via gridDim.z (EPI=4 writes bf16 partials).
// EPI: 0 = store bf16; 2 = gelu(C+bias) -> bf16; 4 = bf16 partial
template<int EPI>
__global__ __launch_bounds__(256)
void gemm_bt_kernel(const short* __restrict__ A, const short* __restrict__ W,
                    const float* __restrict__ bias, const float* __restrict__ resid,
                    void* __restrict__ out, int N, int K)
{
  __shared__ short As[128*64];
  __shared__ short Ws[128*64];
  const int tid = threadIdx.x;
  const int lane = tid & 63, wid = tid >> 6;
  const int wm = wid >> 1, wn = wid & 1;
  const long arow0 = (long)blockIdx.x * 128;
  const long wrow0 = (long)blockIdx.y * 128;
  const int srow = tid >> 3;
  const int sslot = (tid & 7) ^ (srow & 7);
  const int sdst = (tid >> 3) * 64 + (tid & 7) * 8;

  const int Keff = K / gridDim.z;
  const long kbase = (long)blockIdx.z * Keff;

  f32x4 acc[4][4];
  #pragma unroll
  for (int m = 0; m < 4; m++)
    #pragma unroll
    for (int n = 0; n < 4; n++)
      #pragma unroll
      for (int j = 0; j < 4; j++) acc[m][n][j] = 0.f;

  const int swz = (lane & 7) << 3;
  for (int kt = 0; kt < Keff; kt += 64) {
    #pragma unroll
    for (int i = 0; i < 4; i++)
      gl2lds16(A + (arow0 + i*32 + srow) * (long)K + kbase + kt + sslot*8, &As[i*2048 + sdst]);
    #pragma unroll
    for (int i = 0; i < 4; i++)
      gl2lds16(W + (wrow0 + i*32 + srow) * (long)K + kbase + kt + sslot*8, &Ws[i*2048 + sdst]);
    __syncthreads();                 // compiler drains vmcnt(0) before barrier
    #pragma unroll
    for (int kk = 0; kk < 64; kk += 32) {
      bf16x8 a[4], b[4];
      const int ko = kk + (lane >> 4) * 8;
      #pragma unroll
      for (int m = 0; m < 4; m++) {
        int row = wm*64 + m*16 + (lane & 15);
        a[m] = *(const bf16x8*)&As[(row*64 + ko) ^ swz];
      }
      #pragma unroll
      for (int n = 0; n < 4; n++) {
        int row = wn*64 + n*16 + (lane & 15);
        b[n] = *(const bf16x8*)&Ws[(row*64 + ko) ^ swz];
      }
      #pragma unroll
      for (int m = 0; m < 4; m++)
        #pragma unroll
        for (int n = 0; n < 4; n++)
          acc[m][n] = __builtin_amdgcn_mfma_f32_16x16x32_bf16(a[m], b[n], acc[m][n], 0, 0, 0);
    }
    __syncthreads();                 // reads complete before next overwrite
  }

  // C/D layout: col = lane&15, row = (lane>>4)*4 + j
  const int colf = lane & 15, rowf = (lane >> 4) * 4;
  const long psliceoff = (long)blockIdx.z * ((long)gridDim.x * 128) * N;
  #pragma unroll
  for (int m = 0; m < 4; m++)
    #pragma unroll
    for (int n = 0; n < 4; n++) {
      long col = wrow0 + wn*64 + n*16 + colf;
      #pragma unroll
      for (int j = 0; j < 4; j++) {
        long row = arow0 + wm*64 + m*16 + rowf + j;
        long idx = row * (long)N + col;
        float v = acc[m][n][j];
        if (EPI == 0) {
          ((short*)out)[idx] = f2bf(v);
        } else if (EPI == 2) {
          float t = v + bias[col];
          float ge = 0.5f * t * (1.f + erff(t * 0.70710678118654752f));
          ((short*)out)[idx] = f2bf(ge);
        } else {
          ((short*)out)[psliceoff + idx] = f2bf(v);   // EPI==4: bf16 partial
        }
      }
    }
}

// ------- causal depthwise conv(4)+SiLU, 8-row x 8-ch tiles, zero-padded halo; + softplus(dt) -------
__global__ __launch_bounds__(256) void conv_dt_kernel(
    const short* __restrict__ zx, const float* __restrict__ cw, const float* __restrict__ cb,
    const float* __restrict__ dt_bias,
    short* __restrict__ xh, short* __restrict__ Bo, short* __restrict__ Co, float* __restrict__ dto)
{
  const int r0 = blockIdx.x * 8;
  const int tid = threadIdx.x;
  const bool interior = (r0 & (L_SEQ - 1)) != 0;

  auto conv8 = [&](int c0, auto&& emit) {
    const long col = DINNER + c0;
    f32x4 w[8]; float cbv[8];
    #pragma unroll
    for (int j = 0; j < 8; j++) { w[j] = *(const f32x4*)&cw[(c0 + j) * 4]; cbv[j] = cb[c0 + j]; }
    bf16x8 win[11];
    #pragma unroll
    for (int j = 0; j < 3; j++) {
      bf16x8 z;
      #pragma unroll
      for (int q = 0; q < 8; q++) z[q] = 0;
      win[j] = interior ? *(const bf16x8*)&zx[(long)(r0 - 3 + j) * DIN_PAD + col] : z;
    }
    #pragma unroll
    for (int j = 3; j < 11; j++)
      win[j] = *(const bf16x8*)&zx[(long)(r0 - 3 + j) * DIN_PAD + col];
    #pragma unroll
    for (int i = 0; i < 8; i++) {
      float a[8];
      #pragma unroll
      for (int j = 0; j < 8; j++) a[j] = cbv[j];
      #pragma unroll
      for (int k = 0; k < 4; k++)
        #pragma unroll
        for (int j = 0; j < 8; j++) a[j] = fmaf(bf2f(win[i + k][j]), w[j][k], a[j]);
      bf16x8 o;
      #pragma unroll
      for (int j = 0; j < 8; j++) { float s = a[j] / (1.f + __expf(-a[j])); o[j] = f2bf(s); }
      emit(i, o);
    }
  };

  {
    int c0 = tid * 8;
    conv8(c0, [&](int i, bf16x8 o) {
      *(bf16x8*)&xh[(long)(r0 + i) * DINNER + c0] = o;
    });
  }
  if (tid < 32) {
    int c0 = 2048 + tid * 8;
    conv8(c0, [&](int i, bf16x8 o) {
      if (c0 < 2048 + DSTATE) *(bf16x8*)&Bo[(long)(r0 + i) * DSTATE + (c0 - 2048)] = o;
      else                    *(bf16x8*)&Co[(long)(r0 + i) * DSTATE + (c0 - 2048 - DSTATE)] = o;
    });
  } else if (tid < 36) {
    int h0 = (tid - 32) * 8;
    float db[8];
    #pragma unroll
    for (int j = 0; j < 8; j++) db[j] = dt_bias[h0 + j];
    #pragma unroll
    for (int i = 0; i < 8; i++) {
      bf16x8 v = *(const bf16x8*)&zx[(long)(r0 + i) * DIN_PAD + (DINNER + CONVDIM) + h0];
      f32x4 o0, o1;
      #pragma unroll
      for (int j = 0; j < 8; j++) {
        float t = bf2f(v[j]) + db[j];
        float sp = (t > 20.f) ? t : log1pf(__expf(t));
        if (j < 4) o0[j] = sp; else o1[j - 4] = sp;
      }
      *(f32x4*)&dto[(long)(r0 + i) * NHEADS + h0] = o0;
      *(f32x4*)&dto[(long)(r0 + i) * NHEADS + h0 + 4] = o1;
    }
  }
}

// ================= SSD chunked scan =================

__global__ __launch_bounds__(256) void ssd_states_kernel(
    const short* __restrict__ xh, const short* __restrict__ Bm,
    const float* __restrict__ dtb, const float* __restrict__ A_log,
    float* __restrict__ CS, short* __restrict__ SC)
{
  int bid = blockIdx.x;
  int c = bid & 31, h = (bid >> 5) & 31, b = bid >> 10;
  long r0 = (long)b * L_SEQ + c * CHUNK;
  __shared__ short XT[64*72];
  __shared__ short BwT[128*72];
  __shared__ float ws[64];
  int tid = threadIdx.x;

  if (tid < 64) {
    float dtv = dtb[(r0 + tid)*NHEADS + h];
    float A = -__expf(A_log[h]);
    float v = dtv * A;
    #pragma unroll
    for (int o = 1; o < 64; o <<= 1) { float u = __shfl_up(v, o); if (tid >= o) v += u; }
    CS[(long)bid * 64 + tid] = v;
    float cs63 = __shfl(v, 63);
    ws[tid] = __expf(cs63 - v) * dtv;
  }
  #pragma unroll
  for (int i = 0; i < 2; i++) {
    int e = tid + i*256, tau = e & 63, p0 = (e >> 6) * 8;
    bf16x8 v = *(const bf16x8*)&xh[(r0 + tau)*DINNER + h*64 + p0];
    #pragma unroll
    for (int j = 0; j < 8; j++) XT[(p0 + j)*72 + tau] = v[j];
  }
  __syncthreads();
  #pragma unroll
  for (int i = 0; i < 4; i++) {
    int e = tid + i*256, tau = e & 63, n0 = (e >> 6) * 8;
    float w = ws[tau];
    bf16x8 v = *(const bf16x8*)&Bm[(r0 + tau)*DSTATE + n0];
    #pragma unroll
    for (int j = 0; j < 8; j++) BwT[(n0 + j)*72 + tau] = f2bf(bf2f(v[j]) * w);
  }
  __syncthreads();

  int lane = tid & 63, w = tid >> 6;
  f32x4 acc[8];
  #pragma unroll
  for (int nt = 0; nt < 8; nt++) { acc[nt][0]=0.f; acc[nt][1]=0.f; acc[nt][2]=0.f; acc[nt][3]=0.f; }
  #pragma unroll
  for (int kk = 0; kk < 64; kk += 32) {
    int ko = kk + (lane >> 4) * 8;
    bf16x8 a = *(const bf16x8*)&XT[(w*16 + (lane & 15))*72 + ko];
    #pragma unroll
    for (int nt = 0; nt < 8; nt++) {
      bf16x8 bfr = *(const bf16x8*)&BwT[(nt*16 + (lane & 15))*72 + ko];
      acc[nt] = __builtin_amdgcn_mfma_f32_16x16x32_bf16(a, bfr, acc[nt], 0, 0, 0);
    }
  }
  int colf = lane & 15, rowf = (lane >> 4) * 4;
  long sbase = (long)bid * 8192;
  #pragma unroll
  for (int nt = 0; nt < 8; nt++)
    #pragma unroll
    for (int j = 0; j < 4; j++)
      SC[sbase + (w*16 + rowf + j)*128 + nt*16 + colf] = f2bf(acc[nt][j]);
}

__global__ __launch_bounds__(256) void ssd_prefix_kernel(
    const short* __restrict__ SC, const float* __restrict__ CS, short* __restrict__ HP)
{
  int bid = blockIdx.x;
  int q = bid & 3, bh = bid >> 2;
  int tid = threadIdx.x;
  int p = q*16 + (tid >> 4);
  int n0 = (tid & 15) * 8;
  long base = (long)bh * NCHUNK * 8192 + (long)p*128 + n0;
  float H[8];
  #pragma unroll
  for (int j = 0; j < 8; j++) H[j] = 0.f;
  for (int c = 0; c < NCHUNK; c++) {
    long idx = base + (long)c * 8192;
    bf16x8 sc = *(const bf16x8*)&SC[idx];
    bf16x8 hv;
    #pragma unroll
    for (int j = 0; j < 8; j++) hv[j] = f2bf(H[j]);
    *(bf16x8*)&HP[idx] = hv;
    float r = __expf(CS[((long)bh * NCHUNK + c)*64 + 63]);
    #pragma unroll
    for (int j = 0; j < 8; j++) H[j] = H[j]*r + bf2f(sc[j]);
  }
}

__global__ __launch_bounds__(256) void ssd_out_kernel(
    const short* __restrict__ xh, const short* __restrict__ Bm, const short* __restrict__ Cm,
    const float* __restrict__ dtb, const float* __restrict__ CS,
    const short* __restrict__ HP, const float* __restrict__ Dvec,
    short* __restrict__ y)
{
  int bid = blockIdx.x;
  int c = bid & 31, h = (bid >> 5) & 31, b = bid >> 10;
  long r0 = (long)b * L_SEQ + c * CHUNK;
  __shared__ short Csh[64*136];
  __shared__ short Bsh[64*136];
  __shared__ short Ms[64*72];
  __shared__ short XT[64*72];
  __shared__ float csd[64], dts[64];
  int tid = threadIdx.x;

  if (tid < 64) {
    csd[tid] = CS[(long)bid*64 + tid];
    dts[tid] = dtb[(r0 + tid)*NHEADS + h];
  }
  #pragma unroll
  for (int i = 0; i < 4; i++) {
    int e = tid + i*256, tau = e >> 4, n0 = (e & 15) * 8;
    *(bf16x8*)&Bsh[tau*136 + n0] = *(const bf16x8*)&Bm[(r0 + tau)*DSTATE + n0];
    *(bf16x8*)&Csh[tau*136 + n0] = *(const bf16x8*)&Cm[(r0 + tau)*DSTATE + n0];
  }
  #pragma unroll
  for (int i = 0; i < 2; i++) {
    int e = tid + i*256, tau = e & 63, p0 = (e >> 6) * 8;
    bf16x8 v = *(const bf16x8*)&xh[(r0 + tau)*DINNER + h*64 + p0];
    #pragma unroll
    for (int j = 0; j < 8; j++) XT[(p0 + j)*72 + tau] = v[j];
  }
  __syncthreads();

  int lane = tid & 63, w = tid >> 6;
  int colf = lane & 15, rowf = (lane >> 4) * 4;

  f32x4 g[4];
  #pragma unroll
  for (int tt = 0; tt < 4; tt++) { g[tt][0]=0.f; g[tt][1]=0.f; g[tt][2]=0.f; g[tt][3]=0.f; }
  #pragma unroll
  for (int kk = 0; kk < 128; kk += 32) {
    int ko = kk + (lane >> 4) * 8;
    bf16x8 a = *(const bf16x8*)&Csh[(w*16 + (lane & 15))*136 + ko];
    #pragma unroll
    for (int tt = 0; tt < 4; tt++) {
      bf16x8 bfr = *(const bf16x8*)&Bsh[(tt*16 + (lane & 15))*136 + ko];
      g[tt] = __builtin_amdgcn_mfma_f32_16x16x32_bf16(a, bfr, g[tt], 0, 0, 0);
    }
  }
  #pragma unroll
  for (int tt = 0; tt < 4; tt++)
    #pragma unroll
    for (int j = 0; j < 4; j++) {
      int trow = w*16 + rowf + j;
      int tcol = tt*16 + colf;
      float m = (tcol <= trow) ? __expf(csd[trow] - csd[tcol]) * dts[tcol] * g[tt][j] : 0.f;
      Ms[trow*72 + tcol] = f2bf(m);
    }
  __syncthreads();

  f32x4 yv[4], yi[4];
  #pragma unroll
  for (int pt = 0; pt < 4; pt++) {
    yv[pt][0]=0.f; yv[pt][1]=0.f; yv[pt][2]=0.f; yv[pt][3]=0.f;
    yi[pt][0]=0.f; yi[pt][1]=0.f; yi[pt][2]=0.f; yi[pt][3]=0.f;
  }
  #pragma unroll
  for (int kk = 0; kk < 64; kk += 32) {
    int ko = kk + (lane >> 4) * 8;
    bf16x8 a = *(const bf16x8*)&Ms[(w*16 + (lane & 15))*72 + ko];
    #pragma unroll
    for (int pt = 0; pt < 4; pt++) {
      bf16x8 bfr = *(const bf16x8*)&XT[(pt*16 + (lane & 15))*72 + ko];
      yv[pt] = __builtin_amdgcn_mfma_f32_16x16x32_bf16(a, bfr, yv[pt], 0, 0, 0);
    }
  }
  long hpb = (long)bid * 8192;
  #pragma unroll
  for (int kk = 0; kk < 128; kk += 32) {
    int ko = kk + (lane >> 4) * 8;
    bf16x8 a = *(const bf16x8*)&Csh[(w*16 + (lane & 15))*136 + ko];
    #pragma unroll
    for (int pt = 0; pt < 4; pt++) {
      bf16x8 bfr = *(const bf16x8*)&HP[hpb + (long)(pt*16 + (lane & 15))*128 + ko];
      yi[pt] = __builtin_amdgcn_mfma_f32_16x16x32_bf16(a, bfr, yi[pt], 0, 0, 0);
    }
  }
  float Dh = Dvec[h];
  #pragma unroll
  for (int pt = 0; pt < 4; pt++)
    #pragma unroll
    for (int j = 0; j < 4; j++) {
      int trow = w*16 + rowf + j;
      int pcol = pt*16 + colf;
      float sc_ = __expf(csd[trow]);
      float xv = bf2f(XT[pcol*72 + trow]);
      y[(r0 + trow)*DINNER + h*64 + pcol] = f2bf(yv[pt][j] + sc_*yi[pt][j] + Dh*xv);
    }
}

// ---------------- gate with silu(z), RMS(mean) norm * mnorm_w -> bf16 ----------------
__global__ __launch_bounds__(256) void gate_mnorm_kernel(
    const short* __restrict__ y, const short* __restrict__ zx, const float* __restrict__ mw,
    short* __restrict__ out)
{
  int row = blockIdx.x, tid = threadIdx.x;
  int c0 = tid * 8;
  bf16x8 yv = *(const bf16x8*)&y[(long)row*DINNER + c0];
  bf16x8 zv = *(const bf16x8*)&zx[(long)row*DIN_PAD + c0];
  float g[8]; float ssum = 0.f;
  #pragma unroll
  for (int j = 0; j < 8; j++) {
    float z = bf2f(zv[j]);
    float v = bf2f(yv[j]) * (z / (1.f + __expf(-z)));
    g[j] = v; ssum += v * v;
  }
  for (int o = 32; o; o >>= 1) ssum += __shfl_down(ssum, o);
  __shared__ float red[4];
  if ((tid & 63) == 0) red[tid >> 6] = ssum;
  __syncthreads();
  float tot = red[0] + red[1] + red[2] + red[3];
  float sc = rsqrtf(tot * (1.0f / DINNER) + 1e-5f);
  bf16x8 o;
  #pragma unroll
  for (int j = 0; j < 8; j++) o[j] = f2bf(g[j] * sc * mw[c0 + j]);
  *(bf16x8*)&out[(long)row*DINNER + c0] = o;
}

extern "C" void kernel_launch(void* const* d_in, const int* in_sizes, int n_in,
                              void* d_out, int out_size, void* d_ws, size_t ws_size,
                              hipStream_t stream)
{
  const float* x        = (const float*)d_in[0];
  const float* norm1_w  = (const float*)d_in[1];
  const float* in_proj  = (const float*)d_in[2];
  const float* conv_w   = (const float*)d_in[3];
  const float* conv_b   = (const float*)d_in[4];
  const float* dt_bias  = (const float*)d_in[5];
  const float* A_log    = (const float*)d_in[6];
  const float* Dvec     = (const float*)d_in[7];
  const float* mnorm_w  = (const float*)d_in[8];
  const float* out_proj = (const float*)d_in[9];
  const float* norm2_w  = (const float*)d_in[10];
  const float* mlp_w1   = (const float*)d_in[11];
  const float* mlp_b1   = (const float*)d_in[12];
  const float* mlp_w2   = (const float*)d_in[13];
  const float* mlp_b2   = (const float*)d_in[14];
  float* outp = (float*)d_out;

  uint8_t* wsp = (uint8_t*)d_ws;
  auto take = [&](size_t bytes) { void* p = wsp; wsp += (bytes + 255) & ~(size_t)255; return p; };
  short* W1B  = (short*)take((size_t)DIN_PAD * DMODEL * 2);  // rows 4384..4480 zero
  short* W2B  = (short*)take((size_t)DMODEL * DINNER * 2);
  short* W3B  = (short*)take((size_t)DMLP * DMODEL * 2);
  short* W4B  = (short*)take((size_t)DMODEL * DMLP * 2);
  short* X1B  = (short*)take((size_t)ROWS * DMODEL * 2);
  short* ZX   = (short*)take((size_t)ROWS * DIN_PAD * 2);  // 36.7 MB
  short* XH   = (short*)take((size_t)ROWS * DINNER * 2);
  short* BMb  = (short*)take((size_t)ROWS * DSTATE * 2);
  short* CMb  = (short*)take((size_t)ROWS * DSTATE * 2);
  float* DTb  = (float*)take((size_t)ROWS * NHEADS * 4);
  short* Yb   = (short*)take((size_t)ROWS * DINNER * 2);
  short* YGB  = (short*)take((size_t)ROWS * DINNER * 2);   // 16 MB
  float* X2   = (float*)take((size_t)ROWS * DMODEL * 4);   // 16 MB
  short* X2NB = (short*)take((size_t)ROWS * DMODEL * 2);
  short* H1B  = (short*)take((size_t)ROWS * DMLP * 2);     // 32 MB

  // SSD scratch aliases (lifetimes disjoint):
  short* SC = H1B;          // write K1, read K2   | H1B written at mlp1 (later)
  short* HP = YGB;          // write K2, read K3   | spans YGB+X2, both written later
  float* CS = (float*)X2NB; // write K1, read K2/K3| X2NB written at reduce_norm (later)
  // Split-K bf16 partials (4 x 4096x1024 x 2B = 33.6MB) alias onto ZX (36.7MB, dead after gate_mnorm):
  short* PART = ZX;

  // weight converts (single launch)
  cvt_all_kernel<<<14720, 256, 0, stream>>>(in_proj, out_proj, mlp_w1, mlp_w2, W1B, W2B, W3B, W4B);
  // norm1 -> bf16
  rmsnorm_l2_kernel<<<ROWS, 256, 0, stream>>>(x, norm1_w, X1B);
  // in_proj GEMM -> ZX bf16 (1120 blocks)
  gemm_bt_kernel<0><<<dim3(ROWS/128, DIN_PAD/128), 256, 0, stream>>>(X1B, W1B, nullptr, nullptr, ZX, DIN_PAD, DMODEL);
  // conv + dt (8-row blocks)
  conv_dt_kernel<<<ROWS/8, 256, 0, stream>>>(ZX, conv_w, conv_b, dt_bias, XH, BMb, CMb, DTb);
  // SSD chunked scan
  ssd_states_kernel<<<BATCH*NHEADS*NCHUNK, 256, 0, stream>>>(XH, BMb, DTb, A_log, CS, SC);
  ssd_prefix_kernel<<<BATCH*NHEADS*4, 256, 0, stream>>>(SC, CS, HP);
  ssd_out_kernel<<<BATCH*NHEADS*NCHUNK, 256, 0, stream>>>(XH, BMb, CMb, DTb, CS, HP, Dvec, Yb);
  // gate + mamba RMSNorm -> bf16 (last reader of ZX)
  gate_mnorm_kernel<<<ROWS, 256, 0, stream>>>(Yb, ZX, mnorm_w, YGB);
  // out_proj GEMM split-K=4 (1024 blocks) -> PART bf16; fused reduce(+x)+norm2
  gemm_bt_kernel<4><<<dim3(ROWS/128, DMODEL/128, 4), 256, 0, stream>>>(YGB, W2B, nullptr, nullptr, PART, DMODEL, DINNER);
  reduce_norm_kernel<<<ROWS, 256, 0, stream>>>(PART, x, norm2_w, X2, X2NB);
  // mlp1 GEMM + bias + exact gelu -> bf16 (1024 blocks)
  gemm_bt_kernel<2><<<dim3(ROWS/128, DMLP/128), 256, 0, stream>>>(X2NB, W3B, mlp_b1, nullptr, H1B, DMLP, DMODEL);
  // mlp2 GEMM split-K=4 (1024 blocks) -> PART bf16, reduce(+bias+X2) -> d_out
  gemm_bt_kernel<4><<<dim3(ROWS/128, DMODEL/128, 4), 256, 0, stream>>>(H1B, W4B, nullptr, nullptr, PART, DMODEL, DMLP);
  reduce_split4_kernel<<<2048, 256, 0, stream>>>(PART, X2, mlp_b2, outp);
}

// Round 16
// 328.010 us; speedup vs baseline: 1.0581x; 1.0581x over previous
//
#include <hip/hip_runtime.h>
#include <hip/hip_bf16.h>
#include <cstdint>

#define L_SEQ   2048
#define BATCH   2
#define ROWS    (BATCH*L_SEQ)     // 4096
#define DMODEL  1024
#define DINNER  2048
#define DSTATE  128
#define NHEADS  32
#define DIN_PROJ 4384
#define DIN_PAD  4480             // padded to multiple of 128 for BN tiles
#define CONVDIM  2304
#define DMLP    4096
#define CHUNK   64
#define NCHUNK  (L_SEQ/CHUNK)     // 32

typedef __attribute__((ext_vector_type(4))) float f32x4;
typedef __attribute__((ext_vector_type(8))) short bf16x8;
typedef __attribute__((ext_vector_type(4))) short bf16x4;
typedef __attribute__((ext_vector_type(2))) short bf16x2;

static __device__ __forceinline__ short f2bf(float f) {
  union { float f; unsigned int i; } v; v.f = f;
  unsigned int r = v.i + 0x7fffu + ((v.i >> 16) & 1u);  // round-to-nearest-even
  return (short)(r >> 16);
}
static __device__ __forceinline__ float bf2f(short s) {
  union { unsigned int i; float f; } v; v.i = ((unsigned int)(unsigned short)s) << 16;
  return v.f;
}

static __device__ __forceinline__ void gl2lds16(const void* g, void* l) {
  __builtin_amdgcn_global_load_lds((const __attribute__((address_space(1))) void*)g,
                                   (__attribute__((address_space(3))) void*)l, 16, 0, 0);
}

// ---------------- merged fp32 -> bf16 weight convert (4 weights, 1 launch) ----------------
__global__ __launch_bounds__(256) void cvt_all_kernel(
    const float* __restrict__ w1, const float* __restrict__ w2,
    const float* __restrict__ w3, const float* __restrict__ w4,
    short* __restrict__ d1, short* __restrict__ d2,
    short* __restrict__ d3, short* __restrict__ d4)
{
  int b = blockIdx.x;
  const float* src; short* dst; long rows_src; int kshift;
  if (b < 4480)       { src = w1; dst = d1; rows_src = DIN_PROJ; kshift = 10; }
  else if (b < 6528)  { src = w2; dst = d2; rows_src = DMODEL;   kshift = 11; b -= 4480; }
  else if (b < 10624) { src = w3; dst = d3; rows_src = DMLP;     kshift = 10; b -= 6528; }
  else                { src = w4; dst = d4; rows_src = DMODEL;   kshift = 12; b -= 10624; }
  long i = ((long)b * 256 + threadIdx.x) * 4;
  long r = i >> kshift;
  bf16x4 o;
  if (r < rows_src) {
    f32x4 v = *(const f32x4*)&src[i];
    o[0] = f2bf(v[0]); o[1] = f2bf(v[1]); o[2] = f2bf(v[2]); o[3] = f2bf(v[3]);
  } else {
    o[0] = 0; o[1] = 0; o[2] = 0; o[3] = 0;
  }
  *(bf16x4*)&dst[i] = o;
}

// ---------------- L2-style norm: w * x * rsqrt(sum(x^2) + 1e-6), D=1024 -> bf16 ----------------
__global__ __launch_bounds__(256) void rmsnorm_l2_kernel(const float* __restrict__ in,
                                                         const float* __restrict__ w,
                                                         short* __restrict__ out)
{
  int row = blockIdx.x, tid = threadIdx.x;
  const float* xr = in + (long)row * DMODEL;
  f32x4 v = *(const f32x4*)&xr[tid * 4];
  float s = v[0]*v[0] + v[1]*v[1] + v[2]*v[2] + v[3]*v[3];
  for (int o = 32; o; o >>= 1) s += __shfl_down(s, o);
  __shared__ float red[4];
  if ((tid & 63) == 0) red[tid >> 6] = s;
  __syncthreads();
  float sc = rsqrtf(red[0] + red[1] + red[2] + red[3] + 1e-6f);
  f32x4 wv = *(const f32x4*)&w[tid * 4];
  bf16x4 o;
  #pragma unroll
  for (int j = 0; j < 4; j++) o[j] = f2bf(v[j] * sc * wv[j]);
  *(bf16x4*)&out[(long)row * DMODEL + tid * 4] = o;
}

// ---- fused: X2 = p0+p1+x ; X2NB = norm2(X2) (saves a 16MB pass + launch) ----
__global__ __launch_bounds__(256) void reduce_norm_kernel(
    const float* __restrict__ part, const float* __restrict__ resid,
    const float* __restrict__ w, float* __restrict__ X2, short* __restrict__ out)
{
  int row = blockIdx.x, tid = threadIdx.x;
  long i = (long)row * DMODEL + tid * 4;
  const long MN = (long)ROWS * DMODEL;
  f32x4 p0 = *(const f32x4*)&part[i];
  f32x4 p1 = *(const f32x4*)&part[i + MN];
  f32x4 r = *(const f32x4*)&resid[i];
  f32x4 v;
  float s = 0.f;
  #pragma unroll
  for (int j = 0; j < 4; j++) {
    v[j] = p0[j] + p1[j] + r[j];
    s += v[j] * v[j];
  }
  *(f32x4*)&X2[i] = v;
  for (int o = 32; o; o >>= 1) s += __shfl_down(s, o);
  __shared__ float red[4];
  if ((tid & 63) == 0) red[tid >> 6] = s;
  __syncthreads();
  float sc = rsqrtf(red[0] + red[1] + red[2] + red[3] + 1e-6f);
  f32x4 wv = *(const f32x4*)&w[tid * 4];
  bf16x4 o;
  #pragma unroll
  for (int j = 0; j < 4; j++) o[j] = f2bf(v[j] * sc * wv[j]);
  *(bf16x4*)&out[i] = o;
}

// ------- bf16 GEMM, 128x128 tile, BK=64, STG-deep pipeline + T2 XOR-swizzled LDS -------
// Split-K via gridDim.z (EPI=4 writes f32 partials).
// EPI: 0 = store bf16; 2 = gelu(C+bias) -> bf16; 4 = f32 partial
template<int EPI, int STG>
__global__ __launch_bounds__(256)
void gemm_bt_kernel(const short* __restrict__ A, const short* __restrict__ W,
                    const float* __restrict__ bias, const float* __restrict__ resid,
                    void* __restrict__ out, int N, int K)
{
  __shared__ short As[STG][128*64];
  __shared__ short Ws[STG][128*64];
  const int tid = threadIdx.x;
  const int lane = tid & 63, wid = tid >> 6;
  const int wm = wid >> 1, wn = wid & 1;
  const long arow0 = (long)blockIdx.x * 128;
  const long wrow0 = (long)blockIdx.y * 128;
  const int srow = tid >> 3;
  const int sslot = (tid & 7) ^ (srow & 7);
  const int sdst = (tid >> 3) * 64 + (tid & 7) * 8;

  const int Keff = K / gridDim.z;
  const long kbase = (long)blockIdx.z * Keff;

  f32x4 acc[4][4];
  #pragma unroll
  for (int m = 0; m < 4; m++)
    #pragma unroll
    for (int n = 0; n < 4; n++)
      #pragma unroll
      for (int j = 0; j < 4; j++) acc[m][n][j] = 0.f;

  auto stage = [&](int buf, long kt) {
    #pragma unroll
    for (int i = 0; i < 4; i++)
      gl2lds16(A + (arow0 + i*32 + srow) * (long)K + kt + sslot*8, &As[buf][i*2048 + sdst]);
    #pragma unroll
    for (int i = 0; i < 4; i++)
      gl2lds16(W + (wrow0 + i*32 + srow) * (long)K + kt + sslot*8, &Ws[buf][i*2048 + sdst]);
  };

  const int nt = Keff >> 6;
  #pragma unroll
  for (int s = 0; s < STG - 1; s++) stage(s, kbase + (s << 6));

  const int swz = (lane & 7) << 3;
  for (int t = 0; t < nt; t++) {
    if (t + STG - 1 < nt) {
      stage((t + STG - 1) & (STG - 1), kbase + ((long)(t + STG - 1) << 6));
      asm volatile("s_waitcnt vmcnt(8)"  ::: "memory");
    } else {
      asm volatile("s_waitcnt vmcnt(0)" ::: "memory");
    }
    __builtin_amdgcn_s_barrier();
    __builtin_amdgcn_sched_barrier(0);
    const int cur = t & (STG - 1);
    #pragma unroll
    for (int kk = 0; kk < 64; kk += 32) {
      bf16x8 a[4], b[4];
      const int ko = kk + (lane >> 4) * 8;
      #pragma unroll
      for (int m = 0; m < 4; m++) {
        int row = wm*64 + m*16 + (lane & 15);
        a[m] = *(const bf16x8*)&As[cur][(row*64 + ko) ^ swz];
      }
      #pragma unroll
      for (int n = 0; n < 4; n++) {
        int row = wn*64 + n*16 + (lane & 15);
        b[n] = *(const bf16x8*)&Ws[cur][(row*64 + ko) ^ swz];
      }
      #pragma unroll
      for (int m = 0; m < 4; m++)
        #pragma unroll
        for (int n = 0; n < 4; n++)
          acc[m][n] = __builtin_amdgcn_mfma_f32_16x16x32_bf16(a[m], b[n], acc[m][n], 0, 0, 0);
    }
    asm volatile("s_waitcnt lgkmcnt(0)" ::: "memory");
    __builtin_amdgcn_sched_barrier(0);
    __builtin_amdgcn_s_barrier();
  }

  // C/D layout: col = lane&15, row = (lane>>4)*4 + j
  const int colf = lane & 15, rowf = (lane >> 4) * 4;
  const long psliceoff = (long)blockIdx.z * ((long)gridDim.x * 128) * N;
  #pragma unroll
  for (int m = 0; m < 4; m++)
    #pragma unroll
    for (int n = 0; n < 4; n++) {
      long col = wrow0 + wn*64 + n*16 + colf;
      #pragma unroll
      for (int j = 0; j < 4; j++) {
        long row = arow0 + wm*64 + m*16 + rowf + j;
        long idx = row * (long)N + col;
        float v = acc[m][n][j];
        if (EPI == 0) {
          ((short*)out)[idx] = f2bf(v);
        } else if (EPI == 2) {
          float t = v + bias[col];
          float ge = 0.5f * t * (1.f + erff(t * 0.70710678118654752f));
          ((short*)out)[idx] = f2bf(ge);
        } else {
          ((float*)out)[psliceoff + idx] = v;   // EPI==4: f32 partial
        }
      }
    }
}

// ---------------- split-2 reduce (final): out = p0 + p1 + resid + bias, f32 ----------------
__global__ __launch_bounds__(256) void reduce_split2_kernel(
    const float* __restrict__ part, const float* __restrict__ resid,
    const float* __restrict__ bias, float* __restrict__ out)
{
  long i = ((long)blockIdx.x * 256 + threadIdx.x) * 8;
  const long MN = (long)ROWS * DMODEL;
  f32x4 p00 = *(const f32x4*)&part[i];
  f32x4 p01 = *(const f32x4*)&part[i + 4];
  f32x4 p10 = *(const f32x4*)&part[i + MN];
  f32x4 p11 = *(const f32x4*)&part[i + MN + 4];
  f32x4 r0 = *(const f32x4*)&resid[i];
  f32x4 r1 = *(const f32x4*)&resid[i + 4];
  int c = (int)(i & (DMODEL - 1));
  f32x4 b0 = *(const f32x4*)&bias[c];
  f32x4 b1 = *(const f32x4*)&bias[c + 4];
  f32x4 o0, o1;
  #pragma unroll
  for (int j = 0; j < 4; j++) {
    o0[j] = p00[j] + p10[j] + r0[j] + b0[j];
    o1[j] = p01[j] + p11[j] + r1[j] + b1[j];
  }
  *(f32x4*)&out[i] = o0;
  *(f32x4*)&out[i + 4] = o1;
}

// ------- causal depthwise conv(4)+SiLU, 8-row x 8-ch tiles, zero-padded halo; + softplus(dt) -------
__global__ __launch_bounds__(256) void conv_dt_kernel(
    const short* __restrict__ zx, const float* __restrict__ cw, const float* __restrict__ cb,
    const float* __restrict__ dt_bias,
    short* __restrict__ xh, short* __restrict__ Bo, short* __restrict__ Co, float* __restrict__ dto)
{
  const int r0 = blockIdx.x * 8;
  const int tid = threadIdx.x;
  const bool interior = (r0 & (L_SEQ - 1)) != 0;

  auto conv8 = [&](int c0, auto&& emit) {
    const long col = DINNER + c0;
    f32x4 w[8]; float cbv[8];
    #pragma unroll
    for (int j = 0; j < 8; j++) { w[j] = *(const f32x4*)&cw[(c0 + j) * 4]; cbv[j] = cb[c0 + j]; }
    bf16x8 win[11];
    #pragma unroll
    for (int j = 0; j < 3; j++) {
      bf16x8 z;
      #pragma unroll
      for (int q = 0; q < 8; q++) z[q] = 0;
      win[j] = interior ? *(const bf16x8*)&zx[(long)(r0 - 3 + j) * DIN_PAD + col] : z;
    }
    #pragma unroll
    for (int j = 3; j < 11; j++)
      win[j] = *(const bf16x8*)&zx[(long)(r0 - 3 + j) * DIN_PAD + col];
    #pragma unroll
    for (int i = 0; i < 8; i++) {
      float a[8];
      #pragma unroll
      for (int j = 0; j < 8; j++) a[j] = cbv[j];
      #pragma unroll
      for (int k = 0; k < 4; k++)
        #pragma unroll
        for (int j = 0; j < 8; j++) a[j] = fmaf(bf2f(win[i + k][j]), w[j][k], a[j]);
      bf16x8 o;
      #pragma unroll
      for (int j = 0; j < 8; j++) { float s = a[j] / (1.f + __expf(-a[j])); o[j] = f2bf(s); }
      emit(i, o);
    }
  };

  {
    int c0 = tid * 8;
    conv8(c0, [&](int i, bf16x8 o) {
      *(bf16x8*)&xh[(long)(r0 + i) * DINNER + c0] = o;
    });
  }
  if (tid < 32) {
    int c0 = 2048 + tid * 8;
    conv8(c0, [&](int i, bf16x8 o) {
      if (c0 < 2048 + DSTATE) *(bf16x8*)&Bo[(long)(r0 + i) * DSTATE + (c0 - 2048)] = o;
      else                    *(bf16x8*)&Co[(long)(r0 + i) * DSTATE + (c0 - 2048 - DSTATE)] = o;
    });
  } else if (tid < 36) {
    int h0 = (tid - 32) * 8;
    float db[8];
    #pragma unroll
    for (int j = 0; j < 8; j++) db[j] = dt_bias[h0 + j];
    #pragma unroll
    for (int i = 0; i < 8; i++) {
      bf16x8 v = *(const bf16x8*)&zx[(long)(r0 + i) * DIN_PAD + (DINNER + CONVDIM) + h0];
      f32x4 o0, o1;
      #pragma unroll
      for (int j = 0; j < 8; j++) {
        float t = bf2f(v[j]) + db[j];
        float sp = (t > 20.f) ? t : log1pf(__expf(t));
        if (j < 4) o0[j] = sp; else o1[j - 4] = sp;
      }
      *(f32x4*)&dto[(long)(r0 + i) * NHEADS + h0] = o0;
      *(f32x4*)&dto[(long)(r0 + i) * NHEADS + h0 + 4] = o1;
    }
  }
}

// ================= SSD chunked scan =================

__global__ __launch_bounds__(256) void ssd_states_kernel(
    const short* __restrict__ xh, const short* __restrict__ Bm,
    const float* __restrict__ dtb, const float* __restrict__ A_log,
    float* __restrict__ CS, short* __restrict__ SC)
{
  int bid = blockIdx.x;
  int c = bid & 31, h = (bid >> 5) & 31, b = bid >> 10;
  long r0 = (long)b * L_SEQ + c * CHUNK;
  __shared__ short XT[64*72];
  __shared__ short BwT[128*72];
  __shared__ float ws[64];
  int tid = threadIdx.x;

  if (tid < 64) {
    float dtv = dtb[(r0 + tid)*NHEADS + h];
    float A = -__expf(A_log[h]);
    float v = dtv * A;
    #pragma unroll
    for (int o = 1; o < 64; o <<= 1) { float u = __shfl_up(v, o); if (tid >= o) v += u; }
    CS[(long)bid * 64 + tid] = v;
    float cs63 = __shfl(v, 63);
    ws[tid] = __expf(cs63 - v) * dtv;
  }
  #pragma unroll
  for (int i = 0; i < 2; i++) {
    int e = tid + i*256, tau = e & 63, p0 = (e >> 6) * 8;
    bf16x8 v = *(const bf16x8*)&xh[(r0 + tau)*DINNER + h*64 + p0];
    #pragma unroll
    for (int j = 0; j < 8; j++) XT[(p0 + j)*72 + tau] = v[j];
  }
  __syncthreads();
  #pragma unroll
  for (int i = 0; i < 4; i++) {
    int e = tid + i*256, tau = e & 63, n0 = (e >> 6) * 8;
    float w = ws[tau];
    bf16x8 v = *(const bf16x8*)&Bm[(r0 + tau)*DSTATE + n0];
    #pragma unroll
    for (int j = 0; j < 8; j++) BwT[(n0 + j)*72 + tau] = f2bf(bf2f(v[j]) * w);
  }
  __syncthreads();

  int lane = tid & 63, w = tid >> 6;
  f32x4 acc[8];
  #pragma unroll
  for (int nt = 0; nt < 8; nt++) { acc[nt][0]=0.f; acc[nt][1]=0.f; acc[nt][2]=0.f; acc[nt][3]=0.f; }
  #pragma unroll
  for (int kk = 0; kk < 64; kk += 32) {
    int ko = kk + (lane >> 4) * 8;
    bf16x8 a = *(const bf16x8*)&XT[(w*16 + (lane & 15))*72 + ko];
    #pragma unroll
    for (int nt = 0; nt < 8; nt++) {
      bf16x8 bfr = *(const bf16x8*)&BwT[(nt*16 + (lane & 15))*72 + ko];
      acc[nt] = __builtin_amdgcn_mfma_f32_16x16x32_bf16(a, bfr, acc[nt], 0, 0, 0);
    }
  }
  int colf = lane & 15, rowf = (lane >> 4) * 4;
  long sbase = (long)bid * 8192;
  #pragma unroll
  for (int nt = 0; nt < 8; nt++)
    #pragma unroll
    for (int j = 0; j < 4; j++)
      SC[sbase + (w*16 + rowf + j)*128 + nt*16 + colf] = f2bf(acc[nt][j]);
}

__global__ __launch_bounds__(256) void ssd_prefix_kernel(
    const short* __restrict__ SC, const float* __restrict__ CS, short* __restrict__ HP)
{
  int bid = blockIdx.x;
  int q = bid & 3, bh = bid >> 2;
  int tid = threadIdx.x;
  int p = q*16 + (tid >> 4);
  int n0 = (tid & 15) * 8;
  long base = (long)bh * NCHUNK * 8192 + (long)p*128 + n0;
  float H[8];
  #pragma unroll
  for (int j = 0; j < 8; j++) H[j] = 0.f;
  for (int c = 0; c < NCHUNK; c++) {
    long idx = base + (long)c * 8192;
    bf16x8 sc = *(const bf16x8*)&SC[idx];
    bf16x8 hv;
    #pragma unroll
    for (int j = 0; j < 8; j++) hv[j] = f2bf(H[j]);
    *(bf16x8*)&HP[idx] = hv;
    float r = __expf(CS[((long)bh * NCHUNK + c)*64 + 63]);
    #pragma unroll
    for (int j = 0; j < 8; j++) H[j] = H[j]*r + bf2f(sc[j]);
  }
}

__global__ __launch_bounds__(256) void ssd_out_kernel(
    const short* __restrict__ xh, const short* __restrict__ Bm, const short* __restrict__ Cm,
    const float* __restrict__ dtb, const float* __restrict__ CS,
    const short* __restrict__ HP, const float* __restrict__ Dvec,
    short* __restrict__ y)
{
  int bid = blockIdx.x;
  int c = bid & 31, h = (bid >> 5) & 31, b = bid >> 10;
  long r0 = (long)b * L_SEQ + c * CHUNK;
  __shared__ short Csh[64*136];
  __shared__ short Bsh[64*136];
  __shared__ short Ms[64*72];
  __shared__ short XT[64*72];
  __shared__ float csd[64], dts[64];
  int tid = threadIdx.x;

  if (tid < 64) {
    csd[tid] = CS[(long)bid*64 + tid];
    dts[tid] = dtb[(r0 + tid)*NHEADS + h];
  }
  #pragma unroll
  for (int i = 0; i < 4; i++) {
    int e = tid + i*256, tau = e >> 4, n0 = (e & 15) * 8;
    *(bf16x8*)&Bsh[tau*136 + n0] = *(const bf16x8*)&Bm[(r0 + tau)*DSTATE + n0];
    *(bf16x8*)&Csh[tau*136 + n0] = *(const bf16x8*)&Cm[(r0 + tau)*DSTATE + n0];
  }
  #pragma unroll
  for (int i = 0; i < 2; i++) {
    int e = tid + i*256, tau = e & 63, p0 = (e >> 6) * 8;
    bf16x8 v = *(const bf16x8*)&xh[(r0 + tau)*DINNER + h*64 + p0];
    #pragma unroll
    for (int j = 0; j < 8; j++) XT[(p0 + j)*72 + tau] = v[j];
  }
  __syncthreads();

  int lane = tid & 63, w = tid >> 6;
  int colf = lane & 15, rowf = (lane >> 4) * 4;

  f32x4 g[4];
  #pragma unroll
  for (int tt = 0; tt < 4; tt++) { g[tt][0]=0.f; g[tt][1]=0.f; g[tt][2]=0.f; g[tt][3]=0.f; }
  #pragma unroll
  for (int kk = 0; kk < 128; kk += 32) {
    int ko = kk + (lane >> 4) * 8;
    bf16x8 a = *(const bf16x8*)&Csh[(w*16 + (lane & 15))*136 + ko];
    #pragma unroll
    for (int tt = 0; tt < 4; tt++) {
      bf16x8 bfr = *(const bf16x8*)&Bsh[(tt*16 + (lane & 15))*136 + ko];
      g[tt] = __builtin_amdgcn_mfma_f32_16x16x32_bf16(a, bfr, g[tt], 0, 0, 0);
    }
  }
  #pragma unroll
  for (int tt = 0; tt < 4; tt++)
    #pragma unroll
    for (int j = 0; j < 4; j++) {
      int trow = w*16 + rowf + j;
      int tcol = tt*16 + colf;
      float m = (tcol <= trow) ? __expf(csd[trow] - csd[tcol]) * dts[tcol] * g[tt][j] : 0.f;
      Ms[trow*72 + tcol] = f2bf(m);
    }
  __syncthreads();

  f32x4 yv[4], yi[4];
  #pragma unroll
  for (int pt = 0; pt < 4; pt++) {
    yv[pt][0]=0.f; yv[pt][1]=0.f; yv[pt][2]=0.f; yv[pt][3]=0.f;
    yi[pt][0]=0.f; yi[pt][1]=0.f; yi[pt][2]=0.f; yi[pt][3]=0.f;
  }
  #pragma unroll
  for (int kk = 0; kk < 64; kk += 32) {
    int ko = kk + (lane >> 4) * 8;
    bf16x8 a = *(const bf16x8*)&Ms[(w*16 + (lane & 15))*72 + ko];
    #pragma unroll
    for (int pt = 0; pt < 4; pt++) {
      bf16x8 bfr = *(const bf16x8*)&XT[(pt*16 + (lane & 15))*72 + ko];
      yv[pt] = __builtin_amdgcn_mfma_f32_16x16x32_bf16(a, bfr, yv[pt], 0, 0, 0);
    }
  }
  long hpb = (long)bid * 8192;
  #pragma unroll
  for (int kk = 0; kk < 128; kk += 32) {
    int ko = kk + (lane >> 4) * 8;
    bf16x8 a = *(const bf16x8*)&Csh[(w*16 + (lane & 15))*136 + ko];
    #pragma unroll
    for (int pt = 0; pt < 4; pt++) {
      bf16x8 bfr = *(const bf16x8*)&HP[hpb + (long)(pt*16 + (lane & 15))*128 + ko];
      yi[pt] = __builtin_amdgcn_mfma_f32_16x16x32_bf16(a, bfr, yi[pt], 0, 0, 0);
    }
  }
  float Dh = Dvec[h];
  #pragma unroll
  for (int pt = 0; pt < 4; pt++)
    #pragma unroll
    for (int j = 0; j < 4; j++) {
      int trow = w*16 + rowf + j;
      int pcol = pt*16 + colf;
      float sc_ = __expf(csd[trow]);
      float xv = bf2f(XT[pcol*72 + trow]);
      y[(r0 + trow)*DINNER + h*64 + pcol] = f2bf(yv[pt][j] + sc_*yi[pt][j] + Dh*xv);
    }
}

// ---------------- gate with silu(z), RMS(mean) norm * mnorm_w -> bf16 ----------------
__global__ __launch_bounds__(256) void gate_mnorm_kernel(
    const short* __restrict__ y, const short* __restrict__ zx, const float* __restrict__ mw,
    short* __restrict__ out)
{
  int row = blockIdx.x, tid = threadIdx.x;
  int c0 = tid * 8;
  bf16x8 yv = *(const bf16x8*)&y[(long)row*DINNER + c0];
  bf16x8 zv = *(const bf16x8*)&zx[(long)row*DIN_PAD + c0];
  float g[8]; float ssum = 0.f;
  #pragma unroll
  for (int j = 0; j < 8; j++) {
    float z = bf2f(zv[j]);
    float v = bf2f(yv[j]) * (z / (1.f + __expf(-z)));
    g[j] = v; ssum += v * v;
  }
  for (int o = 32; o; o >>= 1) ssum += __shfl_down(ssum, o);
  __shared__ float red[4];
  if ((tid & 63) == 0) red[tid >> 6] = ssum;
  __syncthreads();
  float tot = red[0] + red[1] + red[2] + red[3];
  float sc = rsqrtf(tot * (1.0f / DINNER) + 1e-5f);
  bf16x8 o;
  #pragma unroll
  for (int j = 0; j < 8; j++) o[j] = f2bf(g[j] * sc * mw[c0 + j]);
  *(bf16x8*)&out[(long)row*DINNER + c0] = o;
}

extern "C" void kernel_launch(void* const* d_in, const int* in_sizes, int n_in,
                              void* d_out, int out_size, void* d_ws, size_t ws_size,
                              hipStream_t stream)
{
  const float* x        = (const float*)d_in[0];
  const float* norm1_w  = (const float*)d_in[1];
  const float* in_proj  = (const float*)d_in[2];
  const float* conv_w   = (const float*)d_in[3];
  const float* conv_b   = (const float*)d_in[4];
  const float* dt_bias  = (const float*)d_in[5];
  const float* A_log    = (const float*)d_in[6];
  const float* Dvec     = (const float*)d_in[7];
  const float* mnorm_w  = (const float*)d_in[8];
  const float* out_proj = (const float*)d_in[9];
  const float* norm2_w  = (const float*)d_in[10];
  const float* mlp_w1   = (const float*)d_in[11];
  const float* mlp_b1   = (const float*)d_in[12];
  const float* mlp_w2   = (const float*)d_in[13];
  const float* mlp_b2   = (const float*)d_in[14];
  float* outp = (float*)d_out;

  uint8_t* wsp = (uint8_t*)d_ws;
  auto take = [&](size_t bytes) { void* p = wsp; wsp += (bytes + 255) & ~(size_t)255; return p; };
  short* W1B  = (short*)take((size_t)DIN_PAD * DMODEL * 2);  // rows 4384..4480 zero
  short* W2B  = (short*)take((size_t)DMODEL * DINNER * 2);
  short* W3B  = (short*)take((size_t)DMLP * DMODEL * 2);
  short* W4B  = (short*)take((size_t)DMODEL * DMLP * 2);
  short* X1B  = (short*)take((size_t)ROWS * DMODEL * 2);
  short* ZX   = (short*)take((size_t)ROWS * DIN_PAD * 2);  // 36.7 MB
  short* XH   = (short*)take((size_t)ROWS * DINNER * 2);
  short* BMb  = (short*)take((size_t)ROWS * DSTATE * 2);
  short* CMb  = (short*)take((size_t)ROWS * DSTATE * 2);
  float* DTb  = (float*)take((size_t)ROWS * NHEADS * 4);
  short* Yb   = (short*)take((size_t)ROWS * DINNER * 2);
  short* YGB  = (short*)take((size_t)ROWS * DINNER * 2);   // 16 MB
  float* X2   = (float*)take((size_t)ROWS * DMODEL * 4);   // 16 MB
  short* X2NB = (short*)take((size_t)ROWS * DMODEL * 2);
  short* H1B  = (short*)take((size_t)ROWS * DMLP * 2);     // 32 MB

  // SSD scratch aliases (lifetimes disjoint):
  short* SC = H1B;          // write K1, read K2   | H1B written at mlp1 (later)
  short* HP = YGB;          // write K2, read K3   | spans YGB+X2, both written later
  float* CS = (float*)X2NB; // write K1, read K2/K3| X2NB written at reduce_norm (later)
  // Split-K f32 partials (2 x 4096x1024 x 4B = 33.6MB) alias onto ZX (36.7MB, dead after gate_mnorm):
  float* PART = (float*)ZX;

  // weight converts (single launch)
  cvt_all_kernel<<<14720, 256, 0, stream>>>(in_proj, out_proj, mlp_w1, mlp_w2, W1B, W2B, W3B, W4B);
  // norm1 -> bf16
  rmsnorm_l2_kernel<<<ROWS, 256, 0, stream>>>(x, norm1_w, X1B);
  // in_proj GEMM -> ZX bf16 (1120 blocks, 128^2 STG=2)
  gemm_bt_kernel<0,2><<<dim3(ROWS/128, DIN_PAD/128), 256, 0, stream>>>(X1B, W1B, nullptr, nullptr, ZX, DIN_PAD, DMODEL);
  // conv + dt (8-row blocks)
  conv_dt_kernel<<<ROWS/8, 256, 0, stream>>>(ZX, conv_w, conv_b, dt_bias, XH, BMb, CMb, DTb);
  // SSD chunked scan
  ssd_states_kernel<<<BATCH*NHEADS*NCHUNK, 256, 0, stream>>>(XH, BMb, DTb, A_log, CS, SC);
  ssd_prefix_kernel<<<BATCH*NHEADS*4, 256, 0, stream>>>(SC, CS, HP);
  ssd_out_kernel<<<BATCH*NHEADS*NCHUNK, 256, 0, stream>>>(XH, BMb, CMb, DTb, CS, HP, Dvec, Yb);
  // gate + mamba RMSNorm -> bf16 (last reader of ZX)
  gate_mnorm_kernel<<<ROWS, 256, 0, stream>>>(Yb, ZX, mnorm_w, YGB);
  // out_proj GEMM split-K=2 -> PART f32; fused reduce(+x)+norm2 -> X2, X2NB
  gemm_bt_kernel<4,2><<<dim3(ROWS/128, DMODEL/128, 2), 256, 0, stream>>>(YGB, W2B, nullptr, nullptr, PART, DMODEL, DINNER);
  reduce_norm_kernel<<<ROWS, 256, 0, stream>>>(PART, x, norm2_w, X2, X2NB);
  // mlp1 GEMM + bias + exact gelu -> bf16 (1024 blocks, STG=2)
  gemm_bt_kernel<2,2><<<dim3(ROWS/128, DMLP/128), 256, 0, stream>>>(X2NB, W3B, mlp_b1, nullptr, H1B, DMLP, DMODEL);
  // mlp2 GEMM split-K=2 -> PART f32, reduce(+bias+X2) -> d_out
  gemm_bt_kernel<4,2><<<dim3(ROWS/128, DMODEL/128, 2), 256, 0, stream>>>(H1B, W4B, nullptr, nullptr, PART, DMODEL, DMLP);
  reduce_split2_kernel<<<2048, 256, 0, stream>>>(PART, X2, mlp_b2, outp);
}